// Round 1
// baseline (2296.839 us; speedup 1.0000x reference)
//
#include <hip/hip_runtime.h>
#include <hip/hip_bf16.h>

#define NCH 256
#define VEC 32896   // 256*257/2
#define MM  8

typedef __attribute__((ext_vector_type(4))) float f32x4;
typedef __attribute__((ext_vector_type(8))) short short8;

// ---------------------------------------------------------------------------
// Stage 1: per-mode Cholesky + FillScaleTriL inverse, output t in tril order.
// Right-looking Cholesky; residual row lives in registers (static chunk
// indexing via panel rotation); column broadcast through 1KB LDS colbuf.
// ---------------------------------------------------------------------------
__global__ __launch_bounds__(256, 1)
void chol_kernel(const float* __restrict__ G, float* __restrict__ t_out) {
    const int m = blockIdx.x;
    const int i = threadIdx.x;                 // row owned by this thread
    const float* A = G + (size_t)m * NCH * NCH;
    float* tv = t_out + (size_t)m * VEC;

    __shared__ float colbuf[NCH];
    __shared__ float dshare[2];                // d, 1/d

    // load full row i into registers (upper-triangle values are harmless:
    // they get garbage updates but are never read)
    float S[8][32];
#pragma unroll
    for (int c = 0; c < 8; ++c) {
#pragma unroll
        for (int k = 0; k < 32; k += 4) {
            const float4 v = *reinterpret_cast<const float4*>(&A[i * NCH + 32 * c + k]);
            S[c][k]     = v.x;
            S[c][k + 1] = v.y;
            S[c][k + 2] = v.z;
            S[c][k + 3] = v.w;
        }
    }

    if (i == 0) {
        const float d = sqrtf(S[0][0]);
        dshare[0] = d;
        dshare[1] = 1.0f / d;
    }
    __syncthreads();

    const int tribase = i * (i + 1) / 2;

    for (int p = 0; p < 8; ++p) {
#pragma unroll
        for (int jl = 0; jl < 32; ++jl) {
            const int j = 32 * p + jl;

            // phase 1: compute column j entries, publish to colbuf + t
            float lij = 0.0f;
            if (i > j) {
                lij = S[0][jl] * dshare[1];
                colbuf[i] = lij;
                tv[tribase + j] = lij;
            } else if (i == j) {
                const float d = dshare[0];
                const float x = d - 1e-5f;
                tv[tribase + j] = x + logf(-expm1f(-x));   // softplus_inverse
            }
            __syncthreads();

            // phase 2: rank-1 update of the residual (broadcast reads only).
            // chunk 0 (current panel): columns > jl
#pragma unroll
            for (int k = jl + 1; k < 32; ++k)
                S[0][k] -= lij * colbuf[32 * p + k];
            // trailing chunks
#pragma unroll
            for (int c = 1; c < 8; ++c) {
                if (c <= 7 - p) {
#pragma unroll
                    for (int k = 0; k < 32; ++k)
                        S[c][k] -= lij * colbuf[32 * (p + c) + k];
                }
            }
            // owner of column j+1 computes next pivot from its fresh residual
            if (i == j + 1) {
                const float nd = (jl < 31) ? S[0][jl + 1] : S[1][0];
                const float d = sqrtf(nd);
                dshare[0] = d;
                dshare[1] = 1.0f / d;
            }
            __syncthreads();
        }
        // rotate chunks down: active chunk is always index 0
#pragma unroll
        for (int c = 0; c < 7; ++c)
#pragma unroll
            for (int k = 0; k < 32; ++k)
                S[c][k] = S[c + 1][k];
    }
}

// ---------------------------------------------------------------------------
// Stage 2: per (s,m): L = tril(t + dev_perm) with softplus diag; C = L*L^T+eps.
// L staged in LDS as bf16 (swizzled), all 256 16x16 C tiles via MFMA.
// ---------------------------------------------------------------------------
__global__ __launch_bounds__(1024)
void syrk_kernel(const float* __restrict__ dev, const float* __restrict__ t_in,
                 float* __restrict__ out) {
    extern __shared__ char smem[];             // 131072 B: bf16 L[256][256], swizzled
    const int bid = blockIdx.x;                // s*8 + m
    const int m   = bid & 7;
    const int tid = threadIdx.x;

    const float* dv = dev  + (size_t)bid * VEC;
    const float* tv = t_in + (size_t)m * VEC;
    float* C = out + (size_t)bid * NCH * NCH;

    // ---- stage L into LDS ----
    for (int it = 0; it < 64; ++it) {
        const int pos = it * 1024 + tid;       // flat square position
        const int r = pos >> 8, c = pos & 255;
        unsigned short val = 0;
        if (c <= r) {
            const int slot = r * (r + 1) / 2 + c;              // tril order
            const int didx = (pos < 32640) ? (pos + 256) : (65535 - pos); // TFP perm
            float u = tv[slot] + dv[didx];
            if (c == r) {
                u = (u > 20.0f) ? u : log1pf(expf(u));         // softplus
                u += 1e-5f;                                    // diag_shift
            }
            __hip_bfloat16 h = __float2bfloat16(u);
            val = *reinterpret_cast<unsigned short*>(&h);
        }
        int byte = (r << 9) + (c << 1);
        byte ^= (r & 7) << 4;                  // bank-conflict swizzle
        *reinterpret_cast<unsigned short*>(smem + byte) = val;
    }
    __syncthreads();

    // ---- MFMA: all 256 16x16 tiles of C = L * L^T ----
    const int lane = tid & 63;
    const int w    = tid >> 6;                 // 16 waves
    const int lrow = lane & 15;
    const int kq   = lane >> 4;                // 0..3

    for (int n = 0; n < 16; ++n) {
        const int tidx = w * 16 + n;
        const int I = tidx >> 4, J = tidx & 15;
        const int nk = ((I < J ? I : J) + 2) >> 1;   // ceil(16*(min+1)/32)
        f32x4 acc = {0.f, 0.f, 0.f, 0.f};
        const int arow = I * 16 + lrow;
        const int brow = J * 16 + lrow;
        for (int k0 = 0; k0 < nk; ++k0) {
            const int k = k0 * 32 + kq * 8;
            int abyte = (arow << 9) + (k << 1); abyte ^= (arow & 7) << 4;
            int bbyte = (brow << 9) + (k << 1); bbyte ^= (brow & 7) << 4;
            const short8 a = *reinterpret_cast<const short8*>(smem + abyte);
            const short8 b = *reinterpret_cast<const short8*>(smem + bbyte);
            acc = __builtin_amdgcn_mfma_f32_16x16x32_bf16(a, b, acc, 0, 0, 0);
        }
        const int crow = I * 16 + kq * 4;
        const int ccol = J * 16 + lrow;
#pragma unroll
        for (int q = 0; q < 4; ++q) {
            float v = acc[q];
            if (crow + q == ccol) v += 1e-6f;   // epsilon * I
            C[(crow + q) * NCH + ccol] = v;
        }
    }
}

// ---------------------------------------------------------------------------
extern "C" void kernel_launch(void* const* d_in, const int* in_sizes, int n_in,
                              void* d_out, int out_size, void* d_ws, size_t ws_size,
                              hipStream_t stream) {
    const float* group_map = (const float*)d_in[0];   // (8,256,256) f32
    const float* dev       = (const float*)d_in[1];   // (64,8,32896) f32
    float* out = (float*)d_out;                       // (64,8,256,256) f32
    float* t_ws = (float*)d_ws;                       // 8*32896 f32 = 1.05 MB

    (void)in_sizes; (void)n_in; (void)out_size; (void)ws_size;

    // allow 128 KiB dynamic LDS for the syrk kernel (idempotent, capture-safe)
    hipFuncSetAttribute((const void*)syrk_kernel,
                        hipFuncAttributeMaxDynamicSharedMemorySize, 131072);

    chol_kernel<<<8, 256, 0, stream>>>(group_map, t_ws);
    syrk_kernel<<<512, 1024, 131072, stream>>>(dev, t_ws, out);
}

// Round 4
// 563.799 us; speedup vs baseline: 4.0739x; 4.0739x over previous
//
#include <hip/hip_runtime.h>
#include <hip/hip_bf16.h>

#define NCH 256
#define VEC 32896   // 256*257/2

typedef __attribute__((ext_vector_type(4)))  float f32x4;
typedef __attribute__((ext_vector_type(8)))  short short8;
typedef __attribute__((ext_vector_type(32))) float f32x32;
typedef __attribute__((ext_vector_type(4)))  unsigned short u16x4;
typedef __attribute__((ext_vector_type(4), aligned(4))) float f32x4u;  // 4B-aligned float4

template <int N> struct ic { static constexpr int value = N; };

template <int C>
__device__ __forceinline__ f32x32& sel(f32x32& a, f32x32& b, f32x32& c, f32x32& d) {
    if constexpr (C == 0) return a;
    else if constexpr (C == 1) return b;
    else if constexpr (C == 2) return c;
    else return d;
}

__device__ __forceinline__ void load_chunk(f32x32& V, const float* src) {
#pragma unroll
    for (int k = 0; k < 32; k += 4) {
        const float4 q = *reinterpret_cast<const float4*>(src + k);
        V[k] = q.x; V[k + 1] = q.y; V[k + 2] = q.z; V[k + 3] = q.w;
    }
}

template <int C, int P>
__device__ __forceinline__ void trail(f32x32& V, const f32x32& Lr,
                                      const float (*Ap)[34], int h, int band) {
    const int gc = 2 * C + h;
    if (gc >= P + 1 && gc <= 2 * band + 1) {   // wave-uniform
#pragma unroll
        for (int k = 0; k < 32; ++k) {
            float acc = V[k];
            const float* rowp = Ap[gc * 32 + k];
#pragma unroll
            for (int q = 0; q < 32; q += 2) {
                const float2 pv = *reinterpret_cast<const float2*>(rowp + q);
                acc = fmaf(-Lr[q],     pv.x, acc);
                acc = fmaf(-Lr[q + 1], pv.y, acc);
            }
            V[k] = acc;
        }
    }
}

// ---------------------------------------------------------------------------
// Stage 1: blocked panel Cholesky (panel width 32) + FillScaleTriL inverse.
// 512 threads: 2 threads per row; each half holds interleaved 32-col chunks
// gc = 2c+h in named ext_vector registers. Per panel: in-wave diag factor
// (shfl), per-row TRSM, rank-32 trailing update from LDS broadcasts.
// ---------------------------------------------------------------------------
__global__ __launch_bounds__(512)
void chol_kernel(const float* __restrict__ G, float* __restrict__ t_out) {
    const int t    = threadIdx.x;
    const int w    = t >> 6;
    const int lane = t & 63;
    // bands w0..w7 = {3,3,2,2,0,0,1,1}; halves {1,0,1,0,0,1,0,1}
    const int band = (0x4B >> (2 * (w >> 1))) & 3;
    const int h    = (0xA5 >> w) & 1;
    const int i    = band * 64 + lane;               // my row

    const float* A  = G + (size_t)blockIdx.x * NCH * NCH;
    float*       tv = t_out + (size_t)blockIdx.x * VEC;

    __shared__ float Ap[256][34];    // published panel L (pad 34: conflict-free broadcast)
    __shared__ float Dblk[32][34];   // diag block / L_pp
    __shared__ float Dinv[32];

    f32x32 v0, v1, v2, v3;           // my row: chunks gc=2c+h (cols gc*32..gc*32+31)
    {
        const float* base = A + (size_t)i * NCH + h * 32;
        load_chunk(v0, base);
        load_chunk(v1, base + 64);
        load_chunk(v2, base + 128);
        load_chunk(v3, base + 192);
    }

    auto panel = [&](auto Pc) {
        constexpr int P = decltype(Pc)::value;
        constexpr int ho = P & 1, lc = P >> 1, pbase = P << 5;

        // --- 1. publish diag block ---
        if (h == ho && (i >> 5) == P) {
            const int r = i & 31;
            f32x32& V = sel<lc>(v0, v1, v2, v3);
#pragma unroll
            for (int k = 0; k < 32; ++k) Dblk[r][k] = V[k];
        }
        __syncthreads();

        // --- 2. factor 32x32 diag block in wave 0 (lane pairs mirror rows) ---
        if (t < 64) {
            const int r = lane & 31;
            f32x32 a;
#pragma unroll
            for (int k = 0; k < 32; ++k) a[k] = Dblk[r][k];
            float mydiag = 1.0f;
#pragma unroll
            for (int j = 0; j < 32; ++j) {
                const float dj  = __shfl(a[j], j);
                const float d   = sqrtf(dj);
                const float inv = 1.0f / d;
                const float lrj = a[j] * inv;
                a[j] = (r == j) ? d : lrj;           // garbage for r<j (finite)
                if (r == j) mydiag = d;
#pragma unroll
                for (int k = j + 1; k < 32; ++k) {
                    const float lkj = __shfl(a[j], k);
                    a[k] = fmaf(-a[j], lkj, a[k]);
                }
            }
            if (lane < 32) {
                const int gr = pbase + r;
                const int tb = gr * (gr + 1) / 2 + pbase;
#pragma unroll
                for (int k = 0; k < 32; ++k) {
                    Dblk[r][k] = a[k];
                    if (k < r) tv[tb + k] = a[k];
                }
                Dinv[r] = 1.0f / mydiag;
                const float x = mydiag - 1e-5f;
                tv[tb + r] = x + logf(-expm1f(-x));  // softplus_inverse
            }
        }
        __syncthreads();

        // --- 3. TRSM rows below panel (owner half), publish to Ap + t ---
        const bool below = (i >= pbase + 32);
        if (h == ho && below) {
            f32x32& V = sel<lc>(v0, v1, v2, v3);
#pragma unroll
            for (int k = 0; k < 32; ++k) {
                float xk = V[k];
#pragma unroll
                for (int q = 0; q < k; ++q) xk = fmaf(-V[q], Dblk[k][q], xk);
                V[k] = xk * Dinv[k];
            }
            const int tb = i * (i + 1) / 2 + pbase;
#pragma unroll
            for (int k = 0; k < 32; ++k) { Ap[i][k] = V[k]; tv[tb + k] = V[k]; }
        }
        __syncthreads();

        // --- 4. trailing rank-32 update ---
        if (below) {
            f32x32 Lr;
            if (h == ho) {
                Lr = sel<lc>(v0, v1, v2, v3);
            } else {
#pragma unroll
                for (int k = 0; k < 32; ++k) Lr[k] = Ap[i][k];
            }
            trail<0, P>(v0, Lr, Ap, h, band);
            trail<1, P>(v1, Lr, Ap, h, band);
            trail<2, P>(v2, Lr, Ap, h, band);
            trail<3, P>(v3, Lr, Ap, h, band);
        }
        __syncthreads();
    };

    panel(ic<0>{}); panel(ic<1>{}); panel(ic<2>{}); panel(ic<3>{});
    panel(ic<4>{}); panel(ic<5>{}); panel(ic<6>{}); panel(ic<7>{});
}

// ---------------------------------------------------------------------------
// Stage 2: per (s,m): L = tril(t + dev_perm) with softplus diag; C = L*L^T+eps.
// Vectorized staging; L in LDS as bf16 (swizzled); MFMA with cached A-frags.
// ---------------------------------------------------------------------------
__global__ __launch_bounds__(1024)
void syrk_kernel(const float* __restrict__ dev, const float* __restrict__ t_in,
                 float* __restrict__ out) {
    extern __shared__ char smem[];             // 131072 B: bf16 L[256][256], swizzled
    const int bid  = blockIdx.x;               // s*8 + m
    const int m    = bid & 7;
    const int tid  = threadIdx.x;
    const int lane = tid & 63;
    const int w    = tid >> 6;                 // 16 waves

    const float* dv = dev  + (size_t)bid * VEC;
    const float* tv = t_in + (size_t)m * VEC;
    float* C = out + (size_t)bid * NCH * NCH;

    // ---- stage L into LDS (one row per wave per iteration; float4 loads) ----
#pragma unroll 4
    for (int it = 0; it < 16; ++it) {
        const int pos = it * 4096 + tid * 4;   // r = it*16 + w (wave-uniform)
        const int r  = pos >> 8;
        const int c0 = pos & 255;              // lane*4
        u16x4 ov = {0, 0, 0, 0};
        if (c0 <= r) {
            float4 dvv;
            if (r < 128) {
                dvv = *reinterpret_cast<const float4*>(dv + pos + 256);
            } else {
                const float4 t4 = *reinterpret_cast<const float4*>(dv + (65532 - pos));
                dvv.x = t4.w; dvv.y = t4.z; dvv.z = t4.y; dvv.w = t4.x;
            }
            const int s0 = r * (r + 1) / 2 + c0;
            const f32x4u tvv = *reinterpret_cast<const f32x4u*>(tv + s0);
            const float dva[4] = {dvv.x, dvv.y, dvv.z, dvv.w};
#pragma unroll
            for (int j = 0; j < 4; ++j) {
                const int c = c0 + j;
                if (c <= r) {
                    float u = tvv[j] + dva[j];
                    if (c == r) {
                        u = (u > 20.0f) ? u : log1pf(expf(u));   // softplus
                        u += 1e-5f;                              // diag_shift
                    }
                    __hip_bfloat16 hb = __float2bfloat16(u);
                    ov[j] = *reinterpret_cast<unsigned short*>(&hb);
                }
            }
        }
        int byte = (r << 9) + (c0 << 1);
        byte ^= (r & 7) << 4;                  // bank-conflict swizzle (8B-align safe)
        *reinterpret_cast<u16x4*>(smem + byte) = ov;
    }
    __syncthreads();

    // ---- MFMA: wave w owns C row-panel I = w; A-fragments cached in regs ----
    const int I    = w;
    const int lrow = lane & 15;
    const int kq   = lane >> 4;                // 0..3
    const int nkmax = (I + 2) >> 1;
    const int arow  = I * 16 + lrow;

    short8 a0 = {0,0,0,0,0,0,0,0}, a1 = a0, a2 = a0, a3 = a0,
           a4 = a0, a5 = a0, a6 = a0, a7 = a0;
#define LOADA(K, AV) if (K < nkmax) { \
        int ab = (arow << 9) + ((K * 32 + kq * 8) << 1); ab ^= (arow & 7) << 4; \
        AV = *reinterpret_cast<const short8*>(smem + ab); }
    LOADA(0, a0) LOADA(1, a1) LOADA(2, a2) LOADA(3, a3)
    LOADA(4, a4) LOADA(5, a5) LOADA(6, a6) LOADA(7, a7)
#undef LOADA

    for (int J = 0; J < 16; ++J) {
        const int nk = ((I < J ? I : J) + 2) >> 1;
        f32x4 acc = {0.f, 0.f, 0.f, 0.f};
        const int brow = J * 16 + lrow;
#define STEP(K, AV) if (K < nk) { \
        int bb = (brow << 9) + ((K * 32 + kq * 8) << 1); bb ^= (brow & 7) << 4; \
        const short8 b = *reinterpret_cast<const short8*>(smem + bb); \
        acc = __builtin_amdgcn_mfma_f32_16x16x32_bf16(AV, b, acc, 0, 0, 0); }
        STEP(0, a0) STEP(1, a1) STEP(2, a2) STEP(3, a3)
        STEP(4, a4) STEP(5, a5) STEP(6, a6) STEP(7, a7)
#undef STEP
        const int crow = I * 16 + kq * 4;
        const int ccol = J * 16 + lrow;
#pragma unroll
        for (int q = 0; q < 4; ++q) {
            float vv = acc[q];
            if (crow + q == ccol) vv += 1e-6f;   // epsilon * I
            C[(crow + q) * NCH + ccol] = vv;
        }
    }
}

// ---------------------------------------------------------------------------
extern "C" void kernel_launch(void* const* d_in, const int* in_sizes, int n_in,
                              void* d_out, int out_size, void* d_ws, size_t ws_size,
                              hipStream_t stream) {
    const float* group_map = (const float*)d_in[0];   // (8,256,256) f32
    const float* dev       = (const float*)d_in[1];   // (64,8,32896) f32
    float* out  = (float*)d_out;                      // (64,8,256,256) f32
    float* t_ws = (float*)d_ws;                       // 8*32896 f32 = 1.05 MB

    (void)in_sizes; (void)n_in; (void)out_size; (void)ws_size;

    (void)hipFuncSetAttribute((const void*)syrk_kernel,
                              hipFuncAttributeMaxDynamicSharedMemorySize, 131072);

    chol_kernel<<<8, 512, 0, stream>>>(group_map, t_ws);
    syrk_kernel<<<512, 1024, 131072, stream>>>(dev, t_ws, out);
}

// Round 5
// 563.536 us; speedup vs baseline: 4.0758x; 1.0005x over previous
//
#include <hip/hip_runtime.h>
#include <hip/hip_bf16.h>

#define NCH 256
#define VEC 32896   // 256*257/2

typedef __attribute__((ext_vector_type(4)))  float f32x4;
typedef __attribute__((ext_vector_type(8)))  short short8;
typedef __attribute__((ext_vector_type(32))) float f32x32;
typedef __attribute__((ext_vector_type(4)))  unsigned short u16x4;
typedef __attribute__((ext_vector_type(4), aligned(4))) float f32x4u;  // 4B-aligned float4

template <int N> struct ic { static constexpr int value = N; };

template <int C>
__device__ __forceinline__ f32x32& sel(f32x32& a, f32x32& b, f32x32& c, f32x32& d) {
    if constexpr (C == 0) return a;
    else if constexpr (C == 1) return b;
    else if constexpr (C == 2) return c;
    else return d;
}

__device__ __forceinline__ void load_chunk(f32x32& V, const float* src) {
#pragma unroll
    for (int k = 0; k < 32; k += 4) {
        const float4 q = *reinterpret_cast<const float4*>(src + k);
        V[k] = q.x; V[k + 1] = q.y; V[k + 2] = q.z; V[k + 3] = q.w;
    }
}

template <int C, int P>
__device__ __forceinline__ void trail(f32x32& V, const f32x32& Lr,
                                      const float (*Ap)[34], int h, int band) {
    const int gc = 2 * C + h;
    if (gc >= P + 1 && gc <= 2 * band + 1) {   // wave-uniform
#pragma unroll
        for (int k = 0; k < 32; ++k) {
            float acc = V[k];
            const float* rowp = Ap[gc * 32 + k];
#pragma unroll
            for (int q = 0; q < 32; q += 2) {
                const float2 pv = *reinterpret_cast<const float2*>(rowp + q);
                acc = fmaf(-Lr[q],     pv.x, acc);
                acc = fmaf(-Lr[q + 1], pv.y, acc);
            }
            V[k] = acc;
        }
    }
}

// ---------------------------------------------------------------------------
// Stage 1: blocked panel Cholesky (panel width 32) + FillScaleTriL inverse.
// 512 threads: 2 threads per row; each half holds interleaved 32-col chunks
// gc = 2c+h in named ext_vector registers. Per panel: in-wave diag factor
// (shfl), per-row TRSM, rank-32 trailing update from LDS broadcasts.
// __launch_bounds__(512, 2): 8 waves/block = 2 waves/SIMD -> 256-VGPR budget.
// Round-4 counters showed VGPR=128 + 23 MB scratch traffic (spill) without it.
// ---------------------------------------------------------------------------
__global__ __launch_bounds__(512, 2)
void chol_kernel(const float* __restrict__ G, float* __restrict__ t_out) {
    const int t    = threadIdx.x;
    const int w    = t >> 6;
    const int lane = t & 63;
    // bands w0..w7 = {3,3,2,2,0,0,1,1}; halves {1,0,1,0,0,1,0,1}
    const int band = (0x4B >> (2 * (w >> 1))) & 3;
    const int h    = (0xA5 >> w) & 1;
    const int i    = band * 64 + lane;               // my row

    const float* A  = G + (size_t)blockIdx.x * NCH * NCH;
    float*       tv = t_out + (size_t)blockIdx.x * VEC;

    __shared__ float Ap[256][34];    // published panel L (pad 34: conflict-free broadcast)
    __shared__ float Dblk[32][34];   // diag block / L_pp
    __shared__ float Dinv[32];

    f32x32 v0, v1, v2, v3;           // my row: chunks gc=2c+h (cols gc*32..gc*32+31)
    {
        const float* base = A + (size_t)i * NCH + h * 32;
        load_chunk(v0, base);
        load_chunk(v1, base + 64);
        load_chunk(v2, base + 128);
        load_chunk(v3, base + 192);
    }

    auto panel = [&](auto Pc) {
        constexpr int P = decltype(Pc)::value;
        constexpr int ho = P & 1, lc = P >> 1, pbase = P << 5;

        // --- 1. publish diag block ---
        if (h == ho && (i >> 5) == P) {
            const int r = i & 31;
            f32x32& V = sel<lc>(v0, v1, v2, v3);
#pragma unroll
            for (int k = 0; k < 32; ++k) Dblk[r][k] = V[k];
        }
        __syncthreads();

        // --- 2. factor 32x32 diag block in wave 0 (lane pairs mirror rows) ---
        if (t < 64) {
            const int r = lane & 31;
            f32x32 a;
#pragma unroll
            for (int k = 0; k < 32; ++k) a[k] = Dblk[r][k];
            float mydiag = 1.0f;
#pragma unroll
            for (int j = 0; j < 32; ++j) {
                const float dj  = __shfl(a[j], j);
                const float d   = sqrtf(dj);
                const float inv = 1.0f / d;
                const float lrj = a[j] * inv;
                a[j] = (r == j) ? d : lrj;           // garbage for r<j (finite)
                if (r == j) mydiag = d;
#pragma unroll
                for (int k = j + 1; k < 32; ++k) {
                    const float lkj = __shfl(a[j], k);
                    a[k] = fmaf(-a[j], lkj, a[k]);
                }
            }
            if (lane < 32) {
                const int gr = pbase + r;
                const int tb = gr * (gr + 1) / 2 + pbase;
#pragma unroll
                for (int k = 0; k < 32; ++k) {
                    Dblk[r][k] = a[k];
                    if (k < r) tv[tb + k] = a[k];
                }
                Dinv[r] = 1.0f / mydiag;
                const float x = mydiag - 1e-5f;
                tv[tb + r] = x + logf(-expm1f(-x));  // softplus_inverse
            }
        }
        __syncthreads();

        // --- 3. TRSM rows below panel (owner half), publish to Ap + t ---
        const bool below = (i >= pbase + 32);
        if (h == ho && below) {
            f32x32& V = sel<lc>(v0, v1, v2, v3);
#pragma unroll
            for (int k = 0; k < 32; ++k) {
                float xk = V[k];
#pragma unroll
                for (int q = 0; q < k; ++q) xk = fmaf(-V[q], Dblk[k][q], xk);
                V[k] = xk * Dinv[k];
            }
            const int tb = i * (i + 1) / 2 + pbase;
#pragma unroll
            for (int k = 0; k < 32; ++k) { Ap[i][k] = V[k]; tv[tb + k] = V[k]; }
        }
        __syncthreads();

        // --- 4. trailing rank-32 update ---
        if (below) {
            f32x32 Lr;
            if (h == ho) {
                Lr = sel<lc>(v0, v1, v2, v3);
            } else {
#pragma unroll
                for (int k = 0; k < 32; ++k) Lr[k] = Ap[i][k];
            }
            trail<0, P>(v0, Lr, Ap, h, band);
            trail<1, P>(v1, Lr, Ap, h, band);
            trail<2, P>(v2, Lr, Ap, h, band);
            trail<3, P>(v3, Lr, Ap, h, band);
        }
        __syncthreads();
    };

    panel(ic<0>{}); panel(ic<1>{}); panel(ic<2>{}); panel(ic<3>{});
    panel(ic<4>{}); panel(ic<5>{}); panel(ic<6>{}); panel(ic<7>{});
}

// ---------------------------------------------------------------------------
// Stage 2: per (s,m): L = tril(t + dev_perm) with softplus diag; C = L*L^T+eps.
// Vectorized staging; L in LDS as bf16 (swizzled); MFMA with cached A-frags.
// (Unchanged this round: single-variable experiment; counters next round.)
// ---------------------------------------------------------------------------
__global__ __launch_bounds__(1024)
void syrk_kernel(const float* __restrict__ dev, const float* __restrict__ t_in,
                 float* __restrict__ out) {
    extern __shared__ char smem[];             // 131072 B: bf16 L[256][256], swizzled
    const int bid  = blockIdx.x;               // s*8 + m
    const int m    = bid & 7;
    const int tid  = threadIdx.x;
    const int lane = tid & 63;
    const int w    = tid >> 6;                 // 16 waves

    const float* dv = dev  + (size_t)bid * VEC;
    const float* tv = t_in + (size_t)m * VEC;
    float* C = out + (size_t)bid * NCH * NCH;

    // ---- stage L into LDS (one row per wave per iteration; float4 loads) ----
#pragma unroll 4
    for (int it = 0; it < 16; ++it) {
        const int pos = it * 4096 + tid * 4;   // r = it*16 + w (wave-uniform)
        const int r  = pos >> 8;
        const int c0 = pos & 255;              // lane*4
        u16x4 ov = {0, 0, 0, 0};
        if (c0 <= r) {
            float4 dvv;
            if (r < 128) {
                dvv = *reinterpret_cast<const float4*>(dv + pos + 256);
            } else {
                const float4 t4 = *reinterpret_cast<const float4*>(dv + (65532 - pos));
                dvv.x = t4.w; dvv.y = t4.z; dvv.z = t4.y; dvv.w = t4.x;
            }
            const int s0 = r * (r + 1) / 2 + c0;
            const f32x4u tvv = *reinterpret_cast<const f32x4u*>(tv + s0);
            const float dva[4] = {dvv.x, dvv.y, dvv.z, dvv.w};
#pragma unroll
            for (int j = 0; j < 4; ++j) {
                const int c = c0 + j;
                if (c <= r) {
                    float u = tvv[j] + dva[j];
                    if (c == r) {
                        u = (u > 20.0f) ? u : log1pf(expf(u));   // softplus
                        u += 1e-5f;                              // diag_shift
                    }
                    __hip_bfloat16 hb = __float2bfloat16(u);
                    ov[j] = *reinterpret_cast<unsigned short*>(&hb);
                }
            }
        }
        int byte = (r << 9) + (c0 << 1);
        byte ^= (r & 7) << 4;                  // bank-conflict swizzle (8B-align safe)
        *reinterpret_cast<u16x4*>(smem + byte) = ov;
    }
    __syncthreads();

    // ---- MFMA: wave w owns C row-panel I = w; A-fragments cached in regs ----
    const int I    = w;
    const int lrow = lane & 15;
    const int kq   = lane >> 4;                // 0..3
    const int nkmax = (I + 2) >> 1;
    const int arow  = I * 16 + lrow;

    short8 a0 = {0,0,0,0,0,0,0,0}, a1 = a0, a2 = a0, a3 = a0,
           a4 = a0, a5 = a0, a6 = a0, a7 = a0;
#define LOADA(K, AV) if (K < nkmax) { \
        int ab = (arow << 9) + ((K * 32 + kq * 8) << 1); ab ^= (arow & 7) << 4; \
        AV = *reinterpret_cast<const short8*>(smem + ab); }
    LOADA(0, a0) LOADA(1, a1) LOADA(2, a2) LOADA(3, a3)
    LOADA(4, a4) LOADA(5, a5) LOADA(6, a6) LOADA(7, a7)
#undef LOADA

    for (int J = 0; J < 16; ++J) {
        const int nk = ((I < J ? I : J) + 2) >> 1;
        f32x4 acc = {0.f, 0.f, 0.f, 0.f};
        const int brow = J * 16 + lrow;
#define STEP(K, AV) if (K < nk) { \
        int bb = (brow << 9) + ((K * 32 + kq * 8) << 1); bb ^= (brow & 7) << 4; \
        const short8 b = *reinterpret_cast<const short8*>(smem + bb); \
        acc = __builtin_amdgcn_mfma_f32_16x16x32_bf16(AV, b, acc, 0, 0, 0); }
        STEP(0, a0) STEP(1, a1) STEP(2, a2) STEP(3, a3)
        STEP(4, a4) STEP(5, a5) STEP(6, a6) STEP(7, a7)
#undef STEP
        const int crow = I * 16 + kq * 4;
        const int ccol = J * 16 + lrow;
#pragma unroll
        for (int q = 0; q < 4; ++q) {
            float vv = acc[q];
            if (crow + q == ccol) vv += 1e-6f;   // epsilon * I
            C[(crow + q) * NCH + ccol] = vv;
        }
    }
}

// ---------------------------------------------------------------------------
extern "C" void kernel_launch(void* const* d_in, const int* in_sizes, int n_in,
                              void* d_out, int out_size, void* d_ws, size_t ws_size,
                              hipStream_t stream) {
    const float* group_map = (const float*)d_in[0];   // (8,256,256) f32
    const float* dev       = (const float*)d_in[1];   // (64,8,32896) f32
    float* out  = (float*)d_out;                      // (64,8,256,256) f32
    float* t_ws = (float*)d_ws;                       // 8*32896 f32 = 1.05 MB

    (void)in_sizes; (void)n_in; (void)out_size; (void)ws_size;

    (void)hipFuncSetAttribute((const void*)syrk_kernel,
                              hipFuncAttributeMaxDynamicSharedMemorySize, 131072);

    chol_kernel<<<8, 512, 0, stream>>>(group_map, t_ws);
    syrk_kernel<<<512, 1024, 131072, stream>>>(dev, t_ws, out);
}

// Round 6
// 452.676 us; speedup vs baseline: 5.0739x; 1.2449x over previous
//
#include <hip/hip_runtime.h>
#include <hip/hip_bf16.h>

#define NCH 256
#define VEC 32896   // 256*257/2

typedef __attribute__((ext_vector_type(4)))  float f32x4;
typedef __attribute__((ext_vector_type(8)))  short short8;
typedef __attribute__((ext_vector_type(32))) float f32x32;
typedef __attribute__((ext_vector_type(4)))  unsigned short u16x4;
typedef __attribute__((ext_vector_type(4), aligned(4))) float f32x4u;  // 4B-aligned float4

template <int C>
__device__ __forceinline__ f32x32& sel(f32x32& a, f32x32& b, f32x32& c, f32x32& d) {
    if constexpr (C == 0) return a;
    else if constexpr (C == 1) return b;
    else if constexpr (C == 2) return c;
    else return d;
}

__device__ __forceinline__ void load_chunk(f32x32& V, const float* src) {
#pragma unroll
    for (int k = 0; k < 32; k += 4) {
        const float4 q = *reinterpret_cast<const float4*>(src + k);
        V[k] = q.x; V[k + 1] = q.y; V[k + 2] = q.z; V[k + 3] = q.w;
    }
}

template <int C, int P>
__device__ __forceinline__ void trail(f32x32& V, const f32x32& Lr,
                                      const float (&Ap)[256][34], int h, int band) {
    const int gc = 2 * C + h;
    if (gc >= P + 1 && gc <= 2 * band + 1) {   // wave-uniform
#pragma unroll
        for (int k = 0; k < 32; ++k) {
            float acc = V[k];
            const float* rowp = Ap[gc * 32 + k];
#pragma unroll
            for (int q = 0; q < 32; q += 2) {
                const float2 pv = *reinterpret_cast<const float2*>(rowp + q);
                acc = fmaf(-Lr[q],     pv.x, acc);
                acc = fmaf(-Lr[q + 1], pv.y, acc);
            }
            V[k] = acc;
        }
    }
}

// one panel step, fully inlined so SROA can promote v0..v3 to registers
// (round-5 lesson: a non-inlined generic lambda capturing the vectors by
// reference forced them to scratch: VGPR=128 + 23 MB scratch traffic)
template <int P>
__device__ __forceinline__ void panel_step(
        float* __restrict__ tv, float (&Ap)[256][34], float (&Dblk)[32][34],
        float (&Dinv)[32], f32x32& v0, f32x32& v1, f32x32& v2, f32x32& v3,
        int t, int lane, int h, int band, int i) {
    constexpr int ho = P & 1, lc = P >> 1, pbase = P << 5;

    // --- 1. publish diag block ---
    if (h == ho && (i >> 5) == P) {
        const int r = i & 31;
        f32x32& V = sel<lc>(v0, v1, v2, v3);
#pragma unroll
        for (int k = 0; k < 32; ++k) Dblk[r][k] = V[k];
    }
    __syncthreads();

    // --- 2. factor 32x32 diag block in wave 0 (lane pairs mirror rows) ---
    if (t < 64) {
        const int r = lane & 31;
        f32x32 a;
#pragma unroll
        for (int k = 0; k < 32; ++k) a[k] = Dblk[r][k];
        float mydiag = 1.0f;
#pragma unroll
        for (int j = 0; j < 32; ++j) {
            const float dj  = __shfl(a[j], j);
            const float d   = sqrtf(dj);
            const float inv = 1.0f / d;
            const float lrj = a[j] * inv;
            a[j] = (r == j) ? d : lrj;           // garbage for r<j (finite)
            if (r == j) mydiag = d;
#pragma unroll
            for (int k = j + 1; k < 32; ++k) {
                const float lkj = __shfl(a[j], k);
                a[k] = fmaf(-a[j], lkj, a[k]);
            }
        }
        if (lane < 32) {
            const int gr = pbase + r;
            const int tb = gr * (gr + 1) / 2 + pbase;
#pragma unroll
            for (int k = 0; k < 32; ++k) {
                Dblk[r][k] = a[k];
                if (k < r) tv[tb + k] = a[k];
            }
            Dinv[r] = 1.0f / mydiag;
            const float x = mydiag - 1e-5f;
            tv[tb + r] = x + logf(-expm1f(-x));  // softplus_inverse
        }
    }
    __syncthreads();

    // --- 3. TRSM rows below panel (owner half), publish to Ap + t ---
    const bool below = (i >= pbase + 32);
    if (h == ho && below) {
        f32x32& V = sel<lc>(v0, v1, v2, v3);
#pragma unroll
        for (int k = 0; k < 32; ++k) {
            float xk = V[k];
#pragma unroll
            for (int q = 0; q < k; ++q) xk = fmaf(-V[q], Dblk[k][q], xk);
            V[k] = xk * Dinv[k];
        }
        const int tb = i * (i + 1) / 2 + pbase;
#pragma unroll
        for (int k = 0; k < 32; ++k) { Ap[i][k] = V[k]; tv[tb + k] = V[k]; }
    }
    __syncthreads();

    // --- 4. trailing rank-32 update ---
    if (below) {
        f32x32 Lr;
        if (h == ho) {
            Lr = sel<lc>(v0, v1, v2, v3);
        } else {
#pragma unroll
            for (int k = 0; k < 32; ++k) Lr[k] = Ap[i][k];
        }
        trail<0, P>(v0, Lr, Ap, h, band);
        trail<1, P>(v1, Lr, Ap, h, band);
        trail<2, P>(v2, Lr, Ap, h, band);
        trail<3, P>(v3, Lr, Ap, h, band);
    }
    __syncthreads();
}

// ---------------------------------------------------------------------------
// Stage 1: blocked panel Cholesky (panel width 32) + FillScaleTriL inverse.
// 512 threads: 2 threads per row; each half holds interleaved 32-col chunks
// gc = 2c+h in named ext_vector registers. waves_per_eu(2,2): 8-wave block =
// 2 waves/SIMD -> 256-VGPR budget, scheduler pinned to that occupancy.
// ---------------------------------------------------------------------------
__global__ void __launch_bounds__(512)
__attribute__((amdgpu_waves_per_eu(2, 2)))
chol_kernel(const float* __restrict__ G, float* __restrict__ t_out) {
    const int t    = threadIdx.x;
    const int w    = t >> 6;
    const int lane = t & 63;
    // bands w0..w7 = {3,3,2,2,0,0,1,1}; halves {1,0,1,0,0,1,0,1}
    const int band = (0x4B >> (2 * (w >> 1))) & 3;
    const int h    = (0xA5 >> w) & 1;
    const int i    = band * 64 + lane;               // my row

    const float* A  = G + (size_t)blockIdx.x * NCH * NCH;
    float*       tv = t_out + (size_t)blockIdx.x * VEC;

    __shared__ float Ap[256][34];    // published panel L (pad 34: conflict-free broadcast)
    __shared__ float Dblk[32][34];   // diag block / L_pp
    __shared__ float Dinv[32];

    f32x32 v0, v1, v2, v3;           // my row: chunks gc=2c+h (cols gc*32..gc*32+31)
    {
        const float* base = A + (size_t)i * NCH + h * 32;
        load_chunk(v0, base);
        load_chunk(v1, base + 64);
        load_chunk(v2, base + 128);
        load_chunk(v3, base + 192);
    }

    panel_step<0>(tv, Ap, Dblk, Dinv, v0, v1, v2, v3, t, lane, h, band, i);
    panel_step<1>(tv, Ap, Dblk, Dinv, v0, v1, v2, v3, t, lane, h, band, i);
    panel_step<2>(tv, Ap, Dblk, Dinv, v0, v1, v2, v3, t, lane, h, band, i);
    panel_step<3>(tv, Ap, Dblk, Dinv, v0, v1, v2, v3, t, lane, h, band, i);
    panel_step<4>(tv, Ap, Dblk, Dinv, v0, v1, v2, v3, t, lane, h, band, i);
    panel_step<5>(tv, Ap, Dblk, Dinv, v0, v1, v2, v3, t, lane, h, band, i);
    panel_step<6>(tv, Ap, Dblk, Dinv, v0, v1, v2, v3, t, lane, h, band, i);
    panel_step<7>(tv, Ap, Dblk, Dinv, v0, v1, v2, v3, t, lane, h, band, i);
}

// ---------------------------------------------------------------------------
// Stage 2: per (s,m): L = tril(t + dev_perm) with softplus diag; C = L*L^T+eps.
// Vectorized staging; L in LDS as bf16 (swizzled); MFMA with cached A-frags.
// (Unchanged: waiting for its first counter rows before editing.)
// ---------------------------------------------------------------------------
__global__ __launch_bounds__(1024)
void syrk_kernel(const float* __restrict__ dev, const float* __restrict__ t_in,
                 float* __restrict__ out) {
    extern __shared__ char smem[];             // 131072 B: bf16 L[256][256], swizzled
    const int bid  = blockIdx.x;               // s*8 + m
    const int m    = bid & 7;
    const int tid  = threadIdx.x;
    const int lane = tid & 63;
    const int w    = tid >> 6;                 // 16 waves

    const float* dv = dev  + (size_t)bid * VEC;
    const float* tv = t_in + (size_t)m * VEC;
    float* C = out + (size_t)bid * NCH * NCH;

    // ---- stage L into LDS (one row per wave per iteration; float4 loads) ----
#pragma unroll 4
    for (int it = 0; it < 16; ++it) {
        const int pos = it * 4096 + tid * 4;   // r = it*16 + w (wave-uniform)
        const int r  = pos >> 8;
        const int c0 = pos & 255;              // lane*4
        u16x4 ov = {0, 0, 0, 0};
        if (c0 <= r) {
            float4 dvv;
            if (r < 128) {
                dvv = *reinterpret_cast<const float4*>(dv + pos + 256);
            } else {
                const float4 t4 = *reinterpret_cast<const float4*>(dv + (65532 - pos));
                dvv.x = t4.w; dvv.y = t4.z; dvv.z = t4.y; dvv.w = t4.x;
            }
            const int s0 = r * (r + 1) / 2 + c0;
            const f32x4u tvv = *reinterpret_cast<const f32x4u*>(tv + s0);
            const float dva[4] = {dvv.x, dvv.y, dvv.z, dvv.w};
#pragma unroll
            for (int j = 0; j < 4; ++j) {
                const int c = c0 + j;
                if (c <= r) {
                    float u = tvv[j] + dva[j];
                    if (c == r) {
                        u = (u > 20.0f) ? u : log1pf(expf(u));   // softplus
                        u += 1e-5f;                              // diag_shift
                    }
                    __hip_bfloat16 hb = __float2bfloat16(u);
                    ov[j] = *reinterpret_cast<unsigned short*>(&hb);
                }
            }
        }
        int byte = (r << 9) + (c0 << 1);
        byte ^= (r & 7) << 4;                  // bank-conflict swizzle (8B-align safe)
        *reinterpret_cast<u16x4*>(smem + byte) = ov;
    }
    __syncthreads();

    // ---- MFMA: wave w owns C row-panel I = w; A-fragments cached in regs ----
    const int I    = w;
    const int lrow = lane & 15;
    const int kq   = lane >> 4;                // 0..3
    const int nkmax = (I + 2) >> 1;
    const int arow  = I * 16 + lrow;

    short8 a0 = {0,0,0,0,0,0,0,0}, a1 = a0, a2 = a0, a3 = a0,
           a4 = a0, a5 = a0, a6 = a0, a7 = a0;
#define LOADA(K, AV) if (K < nkmax) { \
        int ab = (arow << 9) + ((K * 32 + kq * 8) << 1); ab ^= (arow & 7) << 4; \
        AV = *reinterpret_cast<const short8*>(smem + ab); }
    LOADA(0, a0) LOADA(1, a1) LOADA(2, a2) LOADA(3, a3)
    LOADA(4, a4) LOADA(5, a5) LOADA(6, a6) LOADA(7, a7)
#undef LOADA

    for (int J = 0; J < 16; ++J) {
        const int nk = ((I < J ? I : J) + 2) >> 1;
        f32x4 acc = {0.f, 0.f, 0.f, 0.f};
        const int brow = J * 16 + lrow;
#define STEP(K, AV) if (K < nk) { \
        int bb = (brow << 9) + ((K * 32 + kq * 8) << 1); bb ^= (brow & 7) << 4; \
        const short8 b = *reinterpret_cast<const short8*>(smem + bb); \
        acc = __builtin_amdgcn_mfma_f32_16x16x32_bf16(AV, b, acc, 0, 0, 0); }
        STEP(0, a0) STEP(1, a1) STEP(2, a2) STEP(3, a3)
        STEP(4, a4) STEP(5, a5) STEP(6, a6) STEP(7, a7)
#undef STEP
        const int crow = I * 16 + kq * 4;
        const int ccol = J * 16 + lrow;
#pragma unroll
        for (int q = 0; q < 4; ++q) {
            float vv = acc[q];
            if (crow + q == ccol) vv += 1e-6f;   // epsilon * I
            C[(crow + q) * NCH + ccol] = vv;
        }
    }
}

// ---------------------------------------------------------------------------
extern "C" void kernel_launch(void* const* d_in, const int* in_sizes, int n_in,
                              void* d_out, int out_size, void* d_ws, size_t ws_size,
                              hipStream_t stream) {
    const float* group_map = (const float*)d_in[0];   // (8,256,256) f32
    const float* dev       = (const float*)d_in[1];   // (64,8,32896) f32
    float* out  = (float*)d_out;                      // (64,8,256,256) f32
    float* t_ws = (float*)d_ws;                       // 8*32896 f32 = 1.05 MB

    (void)in_sizes; (void)n_in; (void)out_size; (void)ws_size;

    (void)hipFuncSetAttribute((const void*)syrk_kernel,
                              hipFuncAttributeMaxDynamicSharedMemorySize, 131072);

    chol_kernel<<<8, 512, 0, stream>>>(group_map, t_ws);
    syrk_kernel<<<512, 1024, 131072, stream>>>(dev, t_ws, out);
}